// Round 3
// baseline (982.657 us; speedup 1.0000x reference)
//
#include <hip/hip_runtime.h>
#include <hip/hip_bf16.h>

#define NN 100000
#define INC 1024
#define HID 128
#define NE 1600000
#define NB ((NN + 255) / 256)   // 391 scan blocks

typedef float floatx4 __attribute__((ext_vector_type(4)));
typedef __bf16 bf16x8 __attribute__((ext_vector_type(8)));
typedef unsigned short ushort8v __attribute__((ext_vector_type(8)));

__device__ __forceinline__ unsigned short f2bf(float f) {
    union { float f; unsigned u; } v; v.f = f;
    unsigned r = v.u + 0x7fffu + ((v.u >> 16) & 1u);   // round-to-nearest-even
    return (unsigned short)(r >> 16);
}

// ---- zero the degree histogram (ws is poisoned 0xAA every call) ----
__global__ __launch_bounds__(256) void init_cnt_k(int* cnt) {
    int i = blockIdx.x * 256 + threadIdx.x;
    if (i < NN) cnt[i] = 0;
}

// ---- histogram destination degrees (excluding self-loop) ----
__global__ __launch_bounds__(256) void deg_edges_k(const int* __restrict__ col, int* cnt) {
    int e = blockIdx.x * 256 + threadIdx.x;
    if (e < NE) atomicAdd(&cnt[col[e]], 1);
}

// ---- dinv[i] = rsqrt(cnt[i] + 1)  (self-loop included) ----
__global__ __launch_bounds__(256) void dinv_k(const int* __restrict__ cnt, float* __restrict__ dinv) {
    int i = blockIdx.x * 256 + threadIdx.x;
    if (i < NN) dinv[i] = rsqrtf((float)(cnt[i] + 1));
}

// ---- exclusive scan, pass 1: per-block (256-wide) ----
__global__ __launch_bounds__(256) void scan1_k(const int* __restrict__ cnt,
                                               int* __restrict__ excl, int* __restrict__ bsum) {
    __shared__ int sh[256];
    const int t = threadIdx.x, b = blockIdx.x;
    const int idx = b * 256 + t;
    const int v = (idx < NN) ? cnt[idx] : 0;
    sh[t] = v;
    __syncthreads();
#pragma unroll
    for (int off = 1; off < 256; off <<= 1) {
        const int x = sh[t];
        const int y = (t >= off) ? sh[t - off] : 0;
        __syncthreads();
        sh[t] = x + y;
        __syncthreads();
    }
    if (idx < NN) excl[idx] = sh[t] - v;
    if (t == 255) bsum[b] = sh[255];
}

// ---- exclusive scan, pass 2: scan the 391 block sums (single block, 512 thr) ----
__global__ __launch_bounds__(512) void scan2_k(const int* __restrict__ bsum, int* __restrict__ boff) {
    __shared__ int sh[512];
    const int t = threadIdx.x;
    const int v = (t < NB) ? bsum[t] : 0;
    sh[t] = v;
    __syncthreads();
#pragma unroll
    for (int off = 1; off < 512; off <<= 1) {
        const int x = sh[t];
        const int y = (t >= off) ? sh[t - off] : 0;
        __syncthreads();
        sh[t] = x + y;
        __syncthreads();
    }
    if (t < NB) boff[t] = sh[t] - v;
}

// ---- scan pass 3: rowptr = excl + boff; also init cursor; rowptr[NN] = NE ----
__global__ __launch_bounds__(256) void scan3_k(const int* __restrict__ excl, const int* __restrict__ boff,
                                               int* __restrict__ rowptr, int* __restrict__ cursor) {
    const int idx = blockIdx.x * 256 + threadIdx.x;
    if (idx < NN) {
        const int v = excl[idx] + boff[blockIdx.x];
        rowptr[idx] = v;
        cursor[idx] = v;
    }
    if (idx == 0) rowptr[NN] = NE;
}

// ---- bucket edges by destination: ssrc[rowptr[c] ...] = srcs of c ----
__global__ __launch_bounds__(256) void fill_k(const int* __restrict__ ei,
                                              int* cursor, int* __restrict__ ssrc) {
    const int e = blockIdx.x * 256 + threadIdx.x;
    if (e < NE) {
        const int r = ei[e];
        const int c = ei[NE + e];
        const int pos = atomicAdd(&cursor[c], 1);
        ssrc[pos] = r;
    }
}

// ---- W [K=1024][N=128] fp32 -> Wt [n][k] bf16 ----
__global__ __launch_bounds__(256) void wt_k(const float* __restrict__ W, unsigned short* __restrict__ Wt) {
    int idx = blockIdx.x * 256 + threadIdx.x;   // 131072 total
    int n = idx >> 10, k = idx & 1023;
    Wt[idx] = f2bf(W[k * HID + n]);
}

// ---- GEMM: hp = (x @ W) * dinv[row] ----
// Barrier-free register GEMM: 128(M)x128(N) block tile, 4 waves,
// each wave owns 2 row-tiles x 8 col-tiles of 16x16x32 MFMA.
// A reuse lives in registers (same wave owns all 8 col-tiles);
// B (Wt, 256 KB bf16) is L2-resident and loaded per-lane from global.
__global__ __launch_bounds__(256) void gemm_hp_k(
    const float* __restrict__ x, const unsigned short* __restrict__ Wt,
    const float* __restrict__ dinv, float* __restrict__ hp)
{
    const int tid  = threadIdx.x;
    const int lane = tid & 63;
    const int wave = tid >> 6;
    const int q    = lane >> 4;     // 0..3
    const int l16  = lane & 15;
    const int brow = blockIdx.x * 128;

    floatx4 acc[2][8];
#pragma unroll
    for (int rt = 0; rt < 2; ++rt)
#pragma unroll
        for (int t = 0; t < 8; ++t) acc[rt][t] = (floatx4){0.f, 0.f, 0.f, 0.f};

    const int r0 = brow + wave * 32 + l16;
    const int r1 = r0 + 16;
    const int c0 = (r0 < NN) ? r0 : (NN - 1);   // clamp; stores guarded below
    const int c1 = (r1 < NN) ? r1 : (NN - 1);
    const float* xp0 = x + (size_t)c0 * INC;
    const float* xp1 = x + (size_t)c1 * INC;
    const unsigned short* wp = Wt + (size_t)l16 * INC;

    for (int k0 = 0; k0 < INC; k0 += 32) {
        const int ko = k0 + q * 8;
        const float4 a0l = *(const float4*)(xp0 + ko);
        const float4 a0h = *(const float4*)(xp0 + ko + 4);
        const float4 a1l = *(const float4*)(xp1 + ko);
        const float4 a1h = *(const float4*)(xp1 + ko + 4);

        union { ushort8v u; bf16x8 b; } af0, af1;
        af0.u[0] = f2bf(a0l.x); af0.u[1] = f2bf(a0l.y); af0.u[2] = f2bf(a0l.z); af0.u[3] = f2bf(a0l.w);
        af0.u[4] = f2bf(a0h.x); af0.u[5] = f2bf(a0h.y); af0.u[6] = f2bf(a0h.z); af0.u[7] = f2bf(a0h.w);
        af1.u[0] = f2bf(a1l.x); af1.u[1] = f2bf(a1l.y); af1.u[2] = f2bf(a1l.z); af1.u[3] = f2bf(a1l.w);
        af1.u[4] = f2bf(a1h.x); af1.u[5] = f2bf(a1h.y); af1.u[6] = f2bf(a1h.z); af1.u[7] = f2bf(a1h.w);

        bf16x8 bf[8];
#pragma unroll
        for (int t = 0; t < 8; ++t)
            bf[t] = *(const bf16x8*)(wp + (size_t)t * 16 * INC + ko);

#pragma unroll
        for (int t = 0; t < 8; ++t) {
            acc[0][t] = __builtin_amdgcn_mfma_f32_16x16x32_bf16(af0.b, bf[t], acc[0][t], 0, 0, 0);
            acc[1][t] = __builtin_amdgcn_mfma_f32_16x16x32_bf16(af1.b, bf[t], acc[1][t], 0, 0, 0);
        }
    }

    // epilogue: C/D map col=lane&15, row=(lane>>4)*4+reg
#pragma unroll
    for (int rt = 0; rt < 2; ++rt) {
#pragma unroll
        for (int r = 0; r < 4; ++r) {
            const int row = brow + wave * 32 + rt * 16 + q * 4 + r;
            if (row < NN) {
                const float d = dinv[row];
#pragma unroll
                for (int t = 0; t < 8; ++t) {
                    const int col = t * 16 + l16;
                    hp[(size_t)row * HID + col] = acc[rt][t][r] * d;
                }
            }
        }
    }
}

// ---- aggregation: one wave per dst; out[d] = dinv[d] * (hp[d] + sum hp[src]) ----
__global__ __launch_bounds__(256) void agg_k(const int* __restrict__ rowptr,
                                             const int* __restrict__ ssrc,
                                             const float* __restrict__ hp,
                                             const float* __restrict__ dinv,
                                             float* __restrict__ out)
{
    const int w = (blockIdx.x * 256 + threadIdx.x) >> 6;   // dst node
    const int lane = threadIdx.x & 63;
    if (w >= NN) return;
    const int s = rowptr[w];
    const int e = rowptr[w + 1];
    const size_t loff = (size_t)lane * 2;

    const float2 self = *(const float2*)&hp[(size_t)w * HID + loff];
    float ax = self.x, ay = self.y;

    for (int i = s; i < e; i += 64) {
        const int rem = e - i;
        const int cnt = rem < 64 ? rem : 64;
        int srcv = 0;
        if (lane < rem) srcv = ssrc[i + lane];
        int j = 0;
        for (; j + 8 <= cnt; j += 8) {
            const int s0 = __shfl(srcv, j + 0);
            const int s1 = __shfl(srcv, j + 1);
            const int s2 = __shfl(srcv, j + 2);
            const int s3 = __shfl(srcv, j + 3);
            const int s4 = __shfl(srcv, j + 4);
            const int s5 = __shfl(srcv, j + 5);
            const int s6 = __shfl(srcv, j + 6);
            const int s7 = __shfl(srcv, j + 7);
            const float2 v0 = *(const float2*)&hp[(size_t)s0 * HID + loff];
            const float2 v1 = *(const float2*)&hp[(size_t)s1 * HID + loff];
            const float2 v2 = *(const float2*)&hp[(size_t)s2 * HID + loff];
            const float2 v3 = *(const float2*)&hp[(size_t)s3 * HID + loff];
            const float2 v4 = *(const float2*)&hp[(size_t)s4 * HID + loff];
            const float2 v5 = *(const float2*)&hp[(size_t)s5 * HID + loff];
            const float2 v6 = *(const float2*)&hp[(size_t)s6 * HID + loff];
            const float2 v7 = *(const float2*)&hp[(size_t)s7 * HID + loff];
            ax += v0.x + v1.x + v2.x + v3.x + v4.x + v5.x + v6.x + v7.x;
            ay += v0.y + v1.y + v2.y + v3.y + v4.y + v5.y + v6.y + v7.y;
        }
        for (; j < cnt; ++j) {
            const int sj = __shfl(srcv, j);
            const float2 v = *(const float2*)&hp[(size_t)sj * HID + loff];
            ax += v.x;
            ay += v.y;
        }
    }

    const float d = dinv[w];
    float2 r;
    r.x = ax * d;
    r.y = ay * d;
    *(float2*)&out[(size_t)w * HID + loff] = r;
}

extern "C" void kernel_launch(void* const* d_in, const int* in_sizes, int n_in,
                              void* d_out, int out_size, void* d_ws, size_t ws_size,
                              hipStream_t stream) {
    const float* x  = (const float*)d_in[0];
    const float* W  = (const float*)d_in[1];
    const int*   ei = (const int*)d_in[2];
    float* out = (float*)d_out;

    // workspace layout (bytes)
    char* p = (char*)d_ws;
    float* hp      = (float*)p;            p += (size_t)NN * HID * 4;   // 51.2 MB
    int*   cnt     = (int*)p;              p += (size_t)NN * 4;
    int*   rowptr  = (int*)p;              p += (size_t)(NN + 4) * 4;
    int*   cursor  = (int*)p;              p += (size_t)NN * 4;
    int*   excl    = (int*)p;              p += (size_t)NN * 4;
    float* dinv    = (float*)p;            p += (size_t)NN * 4;
    unsigned short* Wt = (unsigned short*)p; p += (size_t)INC * HID * 2;
    int*   bsum    = (int*)p;              p += 512 * 4;
    int*   boff    = (int*)p;              p += 512 * 4;
    int*   ssrc    = (int*)p;              p += (size_t)NE * 4;         // 6.4 MB

    init_cnt_k <<<NB, 256, 0, stream>>>(cnt);
    deg_edges_k<<<(NE + 255) / 256, 256, 0, stream>>>(ei + NE, cnt);
    dinv_k     <<<NB, 256, 0, stream>>>(cnt, dinv);
    scan1_k    <<<NB, 256, 0, stream>>>(cnt, excl, bsum);
    scan2_k    <<<1, 512, 0, stream>>>(bsum, boff);
    scan3_k    <<<NB, 256, 0, stream>>>(excl, boff, rowptr, cursor);
    fill_k     <<<(NE + 255) / 256, 256, 0, stream>>>(ei, cursor, ssrc);
    wt_k       <<<(INC * HID) / 256, 256, 0, stream>>>(W, Wt);
    gemm_hp_k  <<<(NN + 127) / 128, 256, 0, stream>>>(x, Wt, dinv, hp);
    agg_k      <<<(NN * 64 + 255) / 256, 256, 0, stream>>>(rowptr, ssrc, hp, dinv, out);
}